// Round 9
// baseline (298.161 us; speedup 1.0000x reference)
//
#include <hip/hip_runtime.h>
#include <cstddef>

static constexpr int B = 64, T = 64, V = 64, C = 65;
static constexpr float NEG   = -1.0e30f;           // log-space "zero"
static constexpr float LOG2E = 1.44269504088896340736f;
static constexpr float LN2   = 0.69314718055994530942f;

// Raw HW transcendentals: v_exp_f32 = 2^x, v_log_f32 = log2(x).
__device__ __forceinline__ float fexp2(float x) {
    float r; asm("v_exp_f32 %0, %1" : "=v"(r) : "v"(x)); return r;
}
__device__ __forceinline__ float flog2(float x) {
    float r; asm("v_log_f32 %0, %1" : "=v"(r) : "v"(x)); return r;
}
// lane i <- lane i-1; lane 0 <- NEG sentinel (folded into the DPP `old`).
__device__ __forceinline__ float shr1(float x, int negi) {
    return __int_as_float(__builtin_amdgcn_update_dpp(
        negi, __float_as_int(x), 0x138 /*wave_shr:1*/, 0xf, 0xf, false));
}

// 126-step anti-diagonal chain, one wave. `sc` may be GLOBAL or LDS
// ([kind][t][v] SoA). SCALAR prefetch arrays (pD/pI/pS) with static
// indices only — r7's float4 pf[] variant went to scratch (rule #20).
// Depth 9: 126 = 14*9, coverage 9*~45 = 405 cy >= IC/L2 latency.
// Alpha goes straight to out (masked dword store, off the chain).
__device__ __forceinline__ void dp_chain_g(const float* __restrict__ sc,
                                           float* __restrict__ outb, int v) {
    const int negi = __float_as_int(NEG);
    float a1 = (v == 0) ? 0.0f : NEG;   // own value, previous diagonal
    float a2 = NEG;                     // own value, two diagonals back
    if (v == 0) outb[0] = 0.0f;         // alpha[0][0]

    constexpr int PD = 9;
    float pD[PD], pI[PD], pS[PD];
    #pragma unroll
    for (int k = 0; k < PD; ++k) {
        const int tc = min(max(1 + k - v, 0), T - 1);
        const int off = tc * V + v;
        pD[k] = sc[off]; pI[k] = sc[T*V + off]; pS[k] = sc[2*T*V + off];
    }
    for (int gq = 0; gq < 14; ++gq) {
        #pragma unroll
        for (int k = 0; k < PD; ++k) {
            const int d = gq * PD + 1 + k;
            const float lf1 = shr1(a1, negi);       // alpha[t,   v-1]
            const float lf2 = shr1(a2, negi);       // alpha[t-1, v-1]
            const float xd = pD[k] + a1;
            const float xs = pS[k] + lf2;
            const float xi = pI[k] + lf1;
            {   // prefetch step d+PD (clamped; stays inside this batch's sc)
                const int tc = min(max(d + PD - v, 0), T - 1);
                const int off = tc * V + v;
                pD[k] = sc[off]; pI[k] = sc[T*V + off]; pS[k] = sc[2*T*V + off];
            }
            const float m = fmaxf(fmaxf(xd, xs), xi);           // v_max3_f32
            const float s = fexp2(xd - m) + fexp2(xs - m) + fexp2(xi - m);
            const float a = m + flog2(s);
            const int t = d - v;
            if (t >= 0 && t < T) outb[t * V + v] = a * LN2;     // masked store
            a2 = a1; a1 = a;
        }
    }
}

// ---- Fused kernel: EXACT round-4 gather geometry (4096 x 192, one pick per
// thread, zero LDS pressure), plus last-arriver-per-batch runs a zero-LDS
// DP chain straight from the just-written g. ----
__global__ void __launch_bounds__(192) fused_kernel(
    const float* __restrict__ as,
    const int* __restrict__ del_ids,    // [B,T]
    const int* __restrict__ ins_ids,    // [B,V]
    const int* __restrict__ sub_ids,    // [B,T,V]
    float* __restrict__ g,              // [B][3][T*V] = 3 MiB (ws)
    int* __restrict__ flags,            // [B] (ws, memset to 0)
    float* __restrict__ out)
{
    __shared__ int isLast;
    const int bt = blockIdx.x, b = bt >> 6, t = bt & 63;
    const int tid = threadIdx.x, v = tid & 63, kind = tid >> 6; // wave-uniform

    // Phase 1: one scattered pick per thread (12288 independent waves).
    {
        int id;
        if (kind == 0)      id = del_ids[bt];
        else if (kind == 1) id = ins_ids[b * V + v];
        else                id = sub_ids[bt * V + v];
        g[((b * 3 + kind) * T + t) * V + v] =
            as[(size_t)(bt * V + v) * C + id] * LOG2E;   // log2-domain
    }
    __syncthreads();                    // drains this block's g-stores (vmcnt 0)
    if (tid == 0) {
        __threadfence();                // release
        isLast = (atomicAdd(flags + b, 1) == T - 1);
        if (isLast) __threadfence();    // acquire other blocks' g-stores
    }
    __syncthreads();
    if (!isLast) return;

    // Phase 2: last arriver for batch b runs its DP (wave 0 only).
    if (tid < 64) dp_chain_g(g + b * 12288, out + b * (T * V), tid);
}

// ---- Fallback (ws too small): one block per batch, gather into LDS,
// then the same chain reading from LDS. ----
__global__ void __launch_bounds__(512) mono_kernel(
    const float* __restrict__ as,
    const int* __restrict__ del_ids, const int* __restrict__ ins_ids,
    const int* __restrict__ sub_ids, float* __restrict__ out)
{
    __shared__ __align__(16) float sc[3 * T * V];
    const int b = blockIdx.x, tid = threadIdx.x;
    for (int p = tid; p < 3 * T * V; p += 512) {
        const int kind = p >> 12;
        const int t = (p >> 6) & 63, v = p & 63;
        int id;
        if (kind == 0)      id = del_ids[b * T + t];
        else if (kind == 1) id = ins_ids[b * V + v];
        else                id = sub_ids[(b * T + t) * V + v];
        sc[p] = as[(size_t)((b * T + t) * V + v) * C + id] * LOG2E;
    }
    __syncthreads();
    if (tid < 64) dp_chain_g(sc, out + b * (T * V), tid);
}

extern "C" void kernel_launch(void* const* d_in, const int* in_sizes, int n_in,
                              void* d_out, int out_size, void* d_ws, size_t ws_size,
                              hipStream_t stream) {
    const float* as      = (const float*)d_in[0];
    const int*   del_ids = (const int*)d_in[1];
    const int*   ins_ids = (const int*)d_in[2];
    const int*   sub_ids = (const int*)d_in[3];
    float*       out     = (float*)d_out;
    const size_t gbytes  = (size_t)B * 3 * T * V * sizeof(float);   // 3 MiB

    if (ws_size >= gbytes + B * sizeof(int)) {
        float* g     = (float*)d_ws;
        int*   flags = (int*)((char*)d_ws + gbytes);
        hipMemsetAsync(flags, 0, B * sizeof(int), stream);
        fused_kernel<<<B * T, 192, 0, stream>>>(as, del_ids, ins_ids, sub_ids,
                                                g, flags, out);
    } else {
        mono_kernel<<<B, 512, 0, stream>>>(as, del_ids, ins_ids, sub_ids, out);
    }
}

// Round 10
// 80.114 us; speedup vs baseline: 3.7217x; 3.7217x over previous
//
#include <hip/hip_runtime.h>
#include <cstddef>

static constexpr int B = 64, T = 64, V = 64, C = 65;
static constexpr float NEG   = -1.0e30f;           // log-space "zero"
static constexpr float LOG2E = 1.44269504088896340736f;
static constexpr float LN2   = 0.69314718055994530942f;

// Raw HW transcendentals: v_exp_f32 = 2^x, v_log_f32 = log2(x).
__device__ __forceinline__ float fexp2(float x) {
    float r; asm("v_exp_f32 %0, %1" : "=v"(r) : "v"(x)); return r;
}
__device__ __forceinline__ float flog2(float x) {
    float r; asm("v_log_f32 %0, %1" : "=v"(r) : "v"(x)); return r;
}
// lane i <- lane i-1; lane 0 <- NEG sentinel (folded into the DPP `old`).
__device__ __forceinline__ float shr1(float x, int negi) {
    return __int_as_float(__builtin_amdgcn_update_dpp(
        negi, __float_as_int(x), 0x138 /*wave_shr:1*/, 0xf, 0xf, false));
}

// 126-step anti-diagonal chain, one wave. sc MUST be LDS (empirical: every
// global-sourced variant spilled to scratch, r7/r9 VGPR=24). Depth-7 scalar
// prefetch; alpha goes masked-direct to out (validated r7/r9), no sAd.
__device__ __forceinline__ void dp_chain(const float* __restrict__ sc,
                                         float* __restrict__ outb, int v) {
    const int negi = __float_as_int(NEG);
    float a1 = (v == 0) ? 0.0f : NEG;   // own value, previous diagonal
    float a2 = NEG;                     // own value, two diagonals back
    if (v == 0) outb[0] = 0.0f;         // alpha[0][0]

    constexpr int PD = 7;               // 126 = 18*7
    float pD[PD], pI[PD], pS[PD];
    #pragma unroll
    for (int k = 0; k < PD; ++k) {
        const int tc = min(max(1 + k - v, 0), T - 1);
        const int off = tc * V + v;
        pD[k] = sc[off]; pI[k] = sc[T*V + off]; pS[k] = sc[2*T*V + off];
    }
    for (int gq = 0; gq < 18; ++gq) {
        #pragma unroll
        for (int k = 0; k < PD; ++k) {
            const int d = gq * PD + 1 + k;
            const float lf1 = shr1(a1, negi);       // alpha[t,   v-1]
            const float lf2 = shr1(a2, negi);       // alpha[t-1, v-1]
            const float xd = pD[k] + a1;
            const float xs = pS[k] + lf2;
            const float xi = pI[k] + lf1;
            {   // prefetch step d+PD (needed ~315 cy later)
                const int tc = min(max(d + PD - v, 0), T - 1);
                const int off = tc * V + v;
                pD[k] = sc[off]; pI[k] = sc[T*V + off]; pS[k] = sc[2*T*V + off];
            }
            const float m = fmaxf(fmaxf(xd, xs), xi);           // v_max3_f32
            const float s = fexp2(xd - m) + fexp2(xs - m) + fexp2(xi - m);
            const float a = m + flog2(s);
            const int t = d - v;
            if (t >= 0 && t < T) outb[t * V + v] = a * LN2;     // masked store
            a2 = a1; a1 = a;
        }
    }
}

// ---- Fused kernel: 1024 blocks x 768 threads (12 waves), 48 KB LDS ->
// 2 blocks/CU = 24 gather-waves/CU all picking (1 pick/thread, 4 (b,t)
// units/block). Last arriver of a batch's 16 blocks stages g into ITS LDS
// and runs the chain (LDS-sourced -> no spill), alpha direct to out. ----
__global__ void __launch_bounds__(768) fused_kernel(
    const float* __restrict__ as,
    const int* __restrict__ del_ids,    // [B,T]
    const int* __restrict__ ins_ids,    // [B,V]
    const int* __restrict__ sub_ids,    // [B,T,V]
    float* __restrict__ g,              // [B][3][T*V] = 3 MiB (ws)
    int* __restrict__ flags,            // [B] (ws, memset to 0)
    float* __restrict__ out)
{
    __shared__ __align__(16) float sc[3 * T * V];   // 48 KB
    __shared__ int isLast;
    const int blk = blockIdx.x, b = blk >> 4, j = blk & 15;
    const int tid = threadIdx.x;

    // Phase 1: one scattered pick per thread. unit u = tid/192 spans exactly
    // 3 waves, so `kind` is wave-uniform; t = j*4 + u.
    {
        const int u = tid / 192, r = tid - u * 192;
        const int kind = r >> 6, v = r & 63;
        const int t = j * 4 + u, bt = b * T + t;
        int id;
        if (kind == 0)      id = del_ids[bt];
        else if (kind == 1) id = ins_ids[b * V + v];
        else                id = sub_ids[bt * V + v];
        g[b * 12288 + kind * 4096 + t * V + v] =
            as[(size_t)(bt * V + v) * C + id] * LOG2E;   // log2-domain
    }
    __syncthreads();                    // all 768 threads' g-stores drained
    if (tid == 0) {
        __threadfence();                // release
        isLast = (atomicAdd(flags + b, 1) == 15);
        if (isLast) __threadfence();    // acquire other blocks' g-stores
    }
    __syncthreads();
    if (!isLast) return;

    // Phase 2: stage batch b's 48 KB into LDS (4 float4 per thread), then
    // wave 0 runs the chain out of LDS.
    {
        const float4* __restrict__ src = (const float4*)(g + b * 12288);
        float4* dst = (float4*)sc;
        #pragma unroll
        for (int k = 0; k < 4; ++k) dst[tid + k * 768] = src[tid + k * 768];
    }
    __syncthreads();
    if (tid < 64) dp_chain(sc, out + b * (T * V), tid);
}

// ---- Fallback: proven round-4/8 two-kernel path ----

__global__ void __launch_bounds__(192) gather_kernel(
    const float* __restrict__ as, const int* __restrict__ del_ids,
    const int* __restrict__ ins_ids, const int* __restrict__ sub_ids,
    float* __restrict__ g)
{
    const int bt = blockIdx.x, b = bt >> 6, t = bt & 63;
    const int tid = threadIdx.x, v = tid & 63, kind = tid >> 6;
    int id;
    if (kind == 0)      id = del_ids[bt];
    else if (kind == 1) id = ins_ids[b * V + v];
    else                id = sub_ids[bt * V + v];
    g[((b * 3 + kind) * T + t) * V + v] =
        as[(size_t)(bt * V + v) * C + id] * LOG2E;
}

__global__ void __launch_bounds__(512) dp_kernel(
    const float* __restrict__ g, float* __restrict__ out)
{
    __shared__ __align__(16) float sc[3 * T * V];
    const int b = blockIdx.x, tid = threadIdx.x;
    {
        const float4* __restrict__ src = (const float4*)(g + (size_t)b * 12288);
        float4* dst = (float4*)sc;
        #pragma unroll
        for (int j = 0; j < 6; ++j) dst[tid + j * 512] = src[tid + j * 512];
    }
    __syncthreads();
    if (tid < 64) dp_chain(sc, out + b * (T * V), tid);
}

extern "C" void kernel_launch(void* const* d_in, const int* in_sizes, int n_in,
                              void* d_out, int out_size, void* d_ws, size_t ws_size,
                              hipStream_t stream) {
    const float* as      = (const float*)d_in[0];
    const int*   del_ids = (const int*)d_in[1];
    const int*   ins_ids = (const int*)d_in[2];
    const int*   sub_ids = (const int*)d_in[3];
    float*       out     = (float*)d_out;
    const size_t gbytes  = (size_t)B * 3 * T * V * sizeof(float);   // 3 MiB

    if (ws_size >= gbytes + B * sizeof(int)) {
        float* g     = (float*)d_ws;
        int*   flags = (int*)((char*)d_ws + gbytes);
        hipMemsetAsync(flags, 0, B * sizeof(int), stream);
        fused_kernel<<<B * 16, 768, 0, stream>>>(as, del_ids, ins_ids, sub_ids,
                                                 g, flags, out);
    } else {
        float* g = (float*)d_ws;
        gather_kernel<<<B * T, 192, 0, stream>>>(as, del_ids, ins_ids, sub_ids, g);
        dp_kernel<<<B, 512, 0, stream>>>(g, out);
    }
}

// Round 11
// 27.906 us; speedup vs baseline: 10.6847x; 2.8709x over previous
//
#include <hip/hip_runtime.h>
#include <cstddef>

static constexpr int B = 64, T = 64, V = 64, C = 65;
static constexpr float NEG   = -1.0e30f;           // log-space "zero"
static constexpr float LOG2E = 1.44269504088896340736f;
static constexpr float LN2   = 0.69314718055994530942f;

// Raw HW transcendentals: v_exp_f32 = 2^x, v_log_f32 = log2(x).
__device__ __forceinline__ float fexp2(float x) {
    float r; asm("v_exp_f32 %0, %1" : "=v"(r) : "v"(x)); return r;
}
__device__ __forceinline__ float flog2(float x) {
    float r; asm("v_log_f32 %0, %1" : "=v"(r) : "v"(x)); return r;
}
// lane i <- lane i-1; lane 0 <- NEG sentinel (folded into the DPP `old`).
__device__ __forceinline__ float shr1(float x, int negi) {
    return __int_as_float(__builtin_amdgcn_update_dpp(
        negi, __float_as_int(x), 0x138 /*wave_shr:1*/, 0xf, 0xf, false));
}

// ---- Gather: proven 4096x192 geometry (one scattered pick per thread,
// 12288 independent waves, ~4 TB/s). Output layout is now PACKED float4
// {del,ins,sub,pad} per (t,v), so the DP step reads ONE ds_read_b128.
// The scattered dword stores are absorbed by L2 (g is 4 MB, write-hot).
__global__ void __launch_bounds__(192) gather_kernel(
    const float* __restrict__ as,
    const int* __restrict__ del_ids,   // [B,T]
    const int* __restrict__ ins_ids,   // [B,V]
    const int* __restrict__ sub_ids,   // [B,T,V]
    float* __restrict__ g)             // [B][T][V][4]
{
    const int bt = blockIdx.x, b = bt >> 6;
    const int tid = threadIdx.x, v = tid & 63, kind = tid >> 6; // wave-uniform
    int id;
    if (kind == 0)      id = del_ids[bt];
    else if (kind == 1) id = ins_ids[b * V + v];
    else                id = sub_ids[bt * V + v];
    g[(size_t)(bt * V + v) * 4 + kind] =
        as[(size_t)(bt * V + v) * C + id] * LOG2E;   // log2-domain scores
}

// 126-step anti-diagonal chain, one wave, LDS-sourced (global-sourced
// variants spill to scratch — r7/r9). ONE ds_read_b128 per step, prefetch
// depth 6 -> max 6 outstanding lgkm events (< the 15-counter limit, so no
// forced drains — the r4 SoA version kept 21 in flight and serialized).
// Alpha goes masked-direct to out (validated r7/r9/r10); no sAd buffer.
__device__ __forceinline__ void dp_chain_p4(const float4* __restrict__ sc4,
                                            float* __restrict__ outb, int v) {
    const int negi = __float_as_int(NEG);
    float a1 = (v == 0) ? 0.0f : NEG;   // own value, previous diagonal
    float a2 = NEG;                     // own value, two diagonals back
    if (v == 0) outb[0] = 0.0f;         // alpha[0][0]

    constexpr int PD = 6;               // 126 = 21*6
    float4 pf[PD];                      // 24 VGPRs, statically indexed
    #pragma unroll
    for (int k = 0; k < PD; ++k) {
        const int tc = min(max(1 + k - v, 0), T - 1);
        pf[k] = sc4[tc * V + v];
    }
    for (int gq = 0; gq < 21; ++gq) {
        #pragma unroll
        for (int k = 0; k < PD; ++k) {
            const int d = gq * PD + 1 + k;
            const float lf1 = shr1(a1, negi);       // alpha[t,   v-1]
            const float lf2 = shr1(a2, negi);       // alpha[t-1, v-1]
            const float xd = pf[k].x + a1;          // del + up
            const float xi = pf[k].y + lf1;         // ins + left
            const float xs = pf[k].z + lf2;         // sub + diag
            {   // prefetch step d+PD (~300 cy ahead; clamped to tile)
                const int tc = min(max(d + PD - v, 0), T - 1);
                pf[k] = sc4[tc * V + v];
            }
            const float m = fmaxf(fmaxf(xd, xs), xi);           // v_max3_f32
            const float s = fexp2(xd - m) + fexp2(xs - m) + fexp2(xi - m);
            const float a = m + flog2(s);
            const int t = d - v;
            if (t >= 0 && t < T) outb[t * V + v] = a * LN2;     // masked store
            a2 = a1; a1 = a;
        }
    }
}

// ---- DP kernel: stage the 64 KB packed tile with 8 waves, chain on wave 0.
__global__ void __launch_bounds__(512) dp_kernel(
    const float* __restrict__ g, float* __restrict__ out)
{
    __shared__ float4 sc4[T * V];       // 64 KB, {d,i,s,pad} per (t,v)
    const int b = blockIdx.x, tid = threadIdx.x;
    {   // 4096 float4s / 512 threads = 8 each, contiguous stream
        const float4* __restrict__ src = (const float4*)(g + (size_t)b * (T * V * 4));
        #pragma unroll
        for (int j = 0; j < 8; ++j) sc4[tid + j * 512] = src[tid + j * 512];
    }
    __syncthreads();
    if (tid < 64) dp_chain_p4(sc4, out + b * (T * V), tid);
}

// ---- Fallback (ws too small): one block per batch, gather into LDS. ----
__global__ void __launch_bounds__(512) mono_kernel(
    const float* __restrict__ as,
    const int* __restrict__ del_ids, const int* __restrict__ ins_ids,
    const int* __restrict__ sub_ids, float* __restrict__ out)
{
    __shared__ float4 sc4[T * V];
    float* scf = (float*)sc4;
    const int b = blockIdx.x, tid = threadIdx.x;
    for (int p = tid; p < 3 * T * V; p += 512) {
        const int kind = p >> 12;
        const int t = (p >> 6) & 63, v = p & 63;
        int id;
        if (kind == 0)      id = del_ids[b * T + t];
        else if (kind == 1) id = ins_ids[b * V + v];
        else                id = sub_ids[(b * T + t) * V + v];
        scf[(t * V + v) * 4 + kind] =
            as[(size_t)((b * T + t) * V + v) * C + id] * LOG2E;
    }
    __syncthreads();
    if (tid < 64) dp_chain_p4(sc4, out + b * (T * V), tid);
}

extern "C" void kernel_launch(void* const* d_in, const int* in_sizes, int n_in,
                              void* d_out, int out_size, void* d_ws, size_t ws_size,
                              hipStream_t stream) {
    const float* as      = (const float*)d_in[0];
    const int*   del_ids = (const int*)d_in[1];
    const int*   ins_ids = (const int*)d_in[2];
    const int*   sub_ids = (const int*)d_in[3];
    float*       out     = (float*)d_out;
    const size_t gbytes  = (size_t)B * T * V * 4 * sizeof(float);   // 4 MiB

    if (ws_size >= gbytes) {
        float* g = (float*)d_ws;
        gather_kernel<<<B * T, 192, 0, stream>>>(as, del_ids, ins_ids, sub_ids, g);
        dp_kernel<<<B, 512, 0, stream>>>(g, out);
    } else {
        mono_kernel<<<B, 512, 0, stream>>>(as, del_ids, ins_ids, sub_ids, out);
    }
}

// Round 12
// 25.494 us; speedup vs baseline: 11.6953x; 1.0946x over previous
//
#include <hip/hip_runtime.h>
#include <cstddef>

static constexpr int B = 64, T = 64, V = 64, C = 65;
static constexpr float NEG   = -1.0e30f;           // log-space "zero"
static constexpr float LOG2E = 1.44269504088896340736f;
static constexpr float LN2   = 0.69314718055994530942f;

// Raw HW transcendentals: v_exp_f32 = 2^x, v_log_f32 = log2(x).
__device__ __forceinline__ float fexp2(float x) {
    float r; asm("v_exp_f32 %0, %1" : "=v"(r) : "v"(x)); return r;
}
__device__ __forceinline__ float flog2(float x) {
    float r; asm("v_log_f32 %0, %1" : "=v"(r) : "v"(x)); return r;
}
// lane i <- lane i-1; lane 0 <- NEG sentinel (folded into the DPP `old`).
__device__ __forceinline__ float shr1(float x, int negi) {
    return __int_as_float(__builtin_amdgcn_update_dpp(
        negi, __float_as_int(x), 0x138 /*wave_shr:1*/, 0xf, 0xf, false));
}

// ---- Gather: 1024 blocks x 192 threads, FOUR picks per thread (4
// consecutive t, fixed kind/v -> kind wave-uniform). Ids first (scalar or
// coalesced), then 4 INDEPENDENT scattered loads batched in flight (4x MLP
// of the r4 one-pick geometry), then coalesced SoA stores (g layout
// [b][kind][t][v] — proven write-friendly; r11's packed stride-16B stores
// regressed via partial-line RMW).
__global__ void __launch_bounds__(192) gather_kernel(
    const float* __restrict__ as,
    const int* __restrict__ del_ids,   // [B,T]
    const int* __restrict__ ins_ids,   // [B,V]
    const int* __restrict__ sub_ids,   // [B,T,V]
    float* __restrict__ g)             // [B][3][T*V]
{
    const int blk = blockIdx.x, b = blk >> 4, j = blk & 15;
    const int tid = threadIdx.x, v = tid & 63, kind = tid >> 6; // wave-uniform
    const int t0 = j * 4;

    int id[4];
    if (kind == 0) {
        #pragma unroll
        for (int k = 0; k < 4; ++k) id[k] = del_ids[b * T + t0 + k]; // scalar
    } else if (kind == 1) {
        const int iv = ins_ids[b * V + v];                           // 1 load
        #pragma unroll
        for (int k = 0; k < 4; ++k) id[k] = iv;
    } else {
        #pragma unroll
        for (int k = 0; k < 4; ++k)
            id[k] = sub_ids[(b * T + t0 + k) * V + v];               // coalesced
    }
    float val[4];
    #pragma unroll
    for (int k = 0; k < 4; ++k)        // 4 independent scattered loads in flight
        val[k] = as[(size_t)((b * T + t0 + k) * V + v) * C + id[k]];
    #pragma unroll
    for (int k = 0; k < 4; ++k)        // coalesced dword stores per kind-row
        g[((b * 3 + kind) * T + t0 + k) * V + v] = val[k] * LOG2E;
}

// 126-step anti-diagonal chain, one wave, LDS SoA source, depth-7 prefetch
// (proven r8 shape, VGPR 132 no-spill). LSE trick: the max term's exp2 is
// exactly 1, so use med3/min3 (full-rate) and spend only TWO quarter-rate
// exp2 per step: s = 1 + exp2(mid-m) + exp2(lo-m). Numerically identical.
__device__ __forceinline__ void dp_chain(const float* __restrict__ sc,
                                         float* __restrict__ sAd, int v) {
    const int negi = __float_as_int(NEG);
    float a1 = (v == 0) ? 0.0f : NEG;
    float a2 = NEG;
    constexpr int PD = 7;                           // 126 = 17*7 + 7
    float pD[PD], pI[PD], pS[PD];
    #pragma unroll
    for (int k = 0; k < PD; ++k) {
        const int tc = min(max(1 + k - v, 0), T - 1);
        const int off = tc * V + v;
        pD[k] = sc[off]; pI[k] = sc[T*V + off]; pS[k] = sc[2*T*V + off];
    }
    for (int gq = 0; gq < 17; ++gq) {
        #pragma unroll
        for (int k = 0; k < PD; ++k) {
            const int d = gq * PD + 1 + k;
            const float lf1 = shr1(a1, negi);       // alpha[t,   v-1]
            const float lf2 = shr1(a2, negi);       // alpha[t-1, v-1]
            const float xd = pD[k] + a1;
            const float xs = pS[k] + lf2;
            const float xi = pI[k] + lf1;
            {   // prefetch step d+PD (needed ~300 cy later)
                const int tc = min(max(d + PD - v, 0), T - 1);
                const int off = tc * V + v;
                pD[k] = sc[off]; pI[k] = sc[T*V + off]; pS[k] = sc[2*T*V + off];
            }
            const float m   = fmaxf(fmaxf(xd, xs), xi);          // v_max3
            const float mid = __builtin_amdgcn_fmed3f(xd, xs, xi); // v_med3
            const float lo  = fminf(fminf(xd, xs), xi);          // v_min3
            const float s   = 1.0f + fexp2(mid - m) + fexp2(lo - m);
            const float a   = m + flog2(s);
            sAd[d * V + v] = a;                     // unconditional, off-chain
            a2 = a1; a1 = a;
        }
    }
    #pragma unroll
    for (int k = 0; k < PD; ++k) {                  // epilogue d = 120..126
        const int d = 120 + k;
        const float lf1 = shr1(a1, negi);
        const float lf2 = shr1(a2, negi);
        const float xd = pD[k] + a1;
        const float xs = pS[k] + lf2;
        const float xi = pI[k] + lf1;
        const float m   = fmaxf(fmaxf(xd, xs), xi);
        const float mid = __builtin_amdgcn_fmed3f(xd, xs, xi);
        const float lo  = fminf(fminf(xd, xs), xi);
        const float s   = 1.0f + fexp2(mid - m) + fexp2(lo - m);
        const float a   = m + flog2(s);
        sAd[d * V + v] = a;
        a2 = a1; a1 = a;
    }
}

// ---- DP kernel: 512 threads; 8-wave stage/writeout, chain on wave 0. ----
__global__ void __launch_bounds__(512) dp_kernel(
    const float* __restrict__ g, float* __restrict__ out)
{
    __shared__ __align__(16) float sc[3 * T * V];   // 48 KB, [kind][t][v]
    __shared__ __align__(16) float sAd[128 * V];    // 32 KB, diag-major alpha
    const int b = blockIdx.x, tid = threadIdx.x;

    {   // stage 48 KB: 6 float4 per thread, one contiguous stream
        const float4* __restrict__ src = (const float4*)(g + (size_t)b * 12288);
        float4* dst = (float4*)sc;
        #pragma unroll
        for (int j = 0; j < 6; ++j) dst[tid + j * 512] = src[tid + j * 512];
    }
    if (tid == 0) sAd[0] = 0.0f;                    // alpha[0][0]
    __syncthreads();
    if (tid < 64) dp_chain(sc, sAd, tid);
    __syncthreads();

    {   // writeout: out[t][v] = sAd[(t+v)*64 + v] * ln2, float4-coalesced
        #pragma unroll
        for (int j = 0; j < 2; ++j) {
            const int idx = tid + j * 512;          // f4 tile 0..1023
            const int t = idx >> 4, v4 = (idx & 15) * 4;
            float4 r;
            r.x = sAd[(t + v4 + 0) * V + v4 + 0] * LN2;
            r.y = sAd[(t + v4 + 1) * V + v4 + 1] * LN2;
            r.z = sAd[(t + v4 + 2) * V + v4 + 2] * LN2;
            r.w = sAd[(t + v4 + 3) * V + v4 + 3] * LN2;
            ((float4*)out)[(size_t)b * 1024 + idx] = r;
        }
    }
}

// ---- Fallback (ws too small): one block per batch, gather into LDS. ----
__global__ void __launch_bounds__(512) mono_kernel(
    const float* __restrict__ as,
    const int* __restrict__ del_ids, const int* __restrict__ ins_ids,
    const int* __restrict__ sub_ids, float* __restrict__ out)
{
    __shared__ __align__(16) float sc[3 * T * V];
    __shared__ __align__(16) float sAd[128 * V];
    const int b = blockIdx.x, tid = threadIdx.x;
    for (int p = tid; p < 3 * T * V; p += 512) {
        const int kind = p >> 12;
        const int t = (p >> 6) & 63, v = p & 63;
        int id;
        if (kind == 0)      id = del_ids[b * T + t];
        else if (kind == 1) id = ins_ids[b * V + v];
        else                id = sub_ids[(b * T + t) * V + v];
        sc[p] = as[(size_t)((b * T + t) * V + v) * C + id] * LOG2E;
    }
    if (tid == 0) sAd[0] = 0.0f;
    __syncthreads();
    if (tid < 64) dp_chain(sc, sAd, tid);
    __syncthreads();
    #pragma unroll
    for (int j = 0; j < 2; ++j) {
        const int idx = tid + j * 512;
        const int t = idx >> 4, v4 = (idx & 15) * 4;
        float4 r;
        r.x = sAd[(t + v4 + 0) * V + v4 + 0] * LN2;
        r.y = sAd[(t + v4 + 1) * V + v4 + 1] * LN2;
        r.z = sAd[(t + v4 + 2) * V + v4 + 2] * LN2;
        r.w = sAd[(t + v4 + 3) * V + v4 + 3] * LN2;
        ((float4*)out)[(size_t)b * 1024 + idx] = r;
    }
}

extern "C" void kernel_launch(void* const* d_in, const int* in_sizes, int n_in,
                              void* d_out, int out_size, void* d_ws, size_t ws_size,
                              hipStream_t stream) {
    const float* as      = (const float*)d_in[0];
    const int*   del_ids = (const int*)d_in[1];
    const int*   ins_ids = (const int*)d_in[2];
    const int*   sub_ids = (const int*)d_in[3];
    float*       out     = (float*)d_out;
    const size_t gbytes  = (size_t)B * 3 * T * V * sizeof(float);   // 3 MiB

    if (ws_size >= gbytes) {
        float* g = (float*)d_ws;
        gather_kernel<<<B * 16, 192, 0, stream>>>(as, del_ids, ins_ids, sub_ids, g);
        dp_kernel<<<B, 512, 0, stream>>>(g, out);
    } else {
        mono_kernel<<<B, 512, 0, stream>>>(as, del_ids, ins_ids, sub_ids, out);
    }
}